// Round 12
// baseline (241.283 us; speedup 1.0000x reference)
//
#include <hip/hip_runtime.h>

typedef _Float16     half8    __attribute__((ext_vector_type(8)));
typedef float        floatx16 __attribute__((ext_vector_type(16)));
typedef float        float4v  __attribute__((ext_vector_type(4)));
typedef unsigned int uint2v   __attribute__((ext_vector_type(2)));
typedef unsigned int uint4v   __attribute__((ext_vector_type(4)));

#define K_DIM 256
#define N_DIM 256
#define NBLK  16384

typedef const __attribute__((address_space(1))) void global_cv_t;
typedef __attribute__((address_space(3))) void lds_v_t;

// W^T in bf8 (e5m2), PLAIN layout wT8[n*256+k]. EXACT: W = +-2^e, e in [-10,-1]
// -> e5m2 normal (exp field 5..14, mantissa 0); bf8->f16 is byte<<8 (exact).
__global__ __launch_bounds__(256) void build_wT8(const float* __restrict__ shift,
                                                 const float* __restrict__ sgn,
                                                 unsigned char* __restrict__ wT8) {
    int idx = blockIdx.x * 256 + threadIdx.x;   // idx = n*256 + k
    int n = idx >> 8, k = idx & 255;
    float sh = shift[k * 256 + n];
    float sg = sgn[k * 256 + n];
    int e = 15 + (int)sh;                       // e5m2 exponent field, 5..14
    wT8[idx] = (unsigned char)(((sg != 0.0f) ? 0x80 : 0) | (e << 2));
}

// R11 structure, N/4 split for 3-block/CU co-residency:
//  - block = 4 waves x 32 rows x 64 cols; 48 KB LDS -> 3 blocks/CU, so
//    generation prologue/tails hide under two sibling blocks' streaming.
//  - all 4 col-quarter blocks of a row group land on the SAME XCD
//    (bid = m*32 + nh*8 + k -> XCD k for every nh), 8 dispatch slots apart
//    -> quarters 2..4 read x from that XCD's L2, not HBM.
//  - vmcnt domain = A-DMA only; one barrier total; per-wave self-sync after it.
__global__ __launch_bounds__(256, 3) void dense_shift_gemm(
        const float* __restrict__ x,
        const unsigned char* __restrict__ wT8,
        const float* __restrict__ bias,
        float* __restrict__ out) {

    // [0, 16K):  B bf8, this block's 64 cols. Local col c (256 B = 16 slots):
    //            phys slot s holds logical s^(c&15) (swizzle on DMA source).
    // [16K,48K): per-wave A f32, 2 buffers of [32 rows][128 B]; phys slot s of
    //            row r holds logical s^(r&7). DMA dest stays linear.
    __shared__ __align__(16) unsigned char lds[49152];

    const int t  = threadIdx.x;
    const int w  = t >> 6;            // wave 0..3
    const int l  = t & 63;
    const int ln = l & 31;
    const int hi = l >> 5;

    // ---- XCD-grouped decomposition: bid = m*32 + nh*8 + k ----
    const int  bid  = blockIdx.x;
    const int  nh   = (bid >> 3) & 3;                      // column quarter 0..3
    const long rg   = (long)(bid & 7) | ((long)(bid >> 5) << 3);  // row group
    const long row0 = (rg * 4 + w) * 32;                   // wave's 32 rows

    // bias first: oldest in FIFO, drained by the prologue vmcnt(0)
    float bv[2];
#pragma unroll
    for (int nb = 0; nb < 2; ++nb) bv[nb] = bias[nh * 64 + nb * 32 + ln];

    // ---- B DMA: 4 instrs/wave, 4 local cols each; source slot pre-XOR'd ----
    {
        const int nL  = l >> 4;       // col within quad
        const int t16 = l & 15;       // dest slot
#pragma unroll
        for (int i = 0; i < 4; ++i) {
            const int nc = w * 16 + i * 4 + nL;            // local col 0..63
            const unsigned char* g = wT8 + (nh * 64 + nc) * 256
                                         + ((t16 ^ (nc & 15)) << 4);
            __builtin_amdgcn_global_load_lds(
                (global_cv_t*)g,
                (lds_v_t*)(lds + (w * 16 + i * 4) * 256), 16, 0, 0);
        }
    }

    // ---- A DMA geometry: instr q covers rows q*8 + (l>>3), slot l&7;
    //      source slot pre-XOR'd by row&7 ----
    const int arow  = l >> 3;                 // 0..7
    const int aslot = l & 7;
    const float* axg = x + (row0 + arow) * (long)K_DIM + (aslot ^ arow) * 4;
    char* aw = (char*)lds + 16384 + w * 8192;

#define ADMA(c_, buf_) do {                                                  \
        _Pragma("unroll")                                                    \
        for (int q = 0; q < 4; ++q) {                                        \
            __builtin_amdgcn_global_load_lds(                                \
                (global_cv_t*)(axg + q * 8 * K_DIM + (c_) * 32),             \
                (lds_v_t*)(aw + (buf_) * 4096 + q * 1024), 16, 0, 0);        \
        }                                                                    \
    } while (0)

    ADMA(0, 0);
    ADMA(1, 1);

    asm volatile("s_waitcnt vmcnt(0)" ::: "memory");   // all DMA landed
    __syncthreads();                                   // the ONLY barrier

    floatx16 acc[2];
#pragma unroll
    for (int nb = 0; nb < 2; ++nb)
#pragma unroll
        for (int r = 0; r < 16; ++r) acc[nb][r] = bv[nb];   // bias pre-folded

    const char* bl    = (const char*)lds;
    const int   sx7   = ln & 7;
    const int   sx15  = ln & 15;
    const char* arp   = aw + ln * 128;        // this lane's A row (+ buf*4096)

#define WAITV(n_) do {                                                       \
        asm volatile("s_waitcnt vmcnt(" #n_ ")" ::: "memory");               \
        __builtin_amdgcn_sched_barrier(0);                                   \
    } while (0)

    // One K=32 chunk: A from own LDS buffer, cvt to f16, overwrite-DMA for
    // chunk i_+2, then B (b64 + exact bf8->f16 unpack) and 4 MFMA.
#define CHUNK(i_, buf_, DMAI) do {                                           \
        const char* ab_ = arp + (buf_) * 4096;                               \
        float4v f00 = *(const float4v*)(ab_ + (((hi * 2    ) ^ sx7) << 4));  \
        float4v f01 = *(const float4v*)(ab_ + (((hi * 2 + 1) ^ sx7) << 4));  \
        float4v f10 = *(const float4v*)(ab_ + (((4 + hi * 2    ) ^ sx7) << 4));\
        float4v f11 = *(const float4v*)(ab_ + (((4 + hi * 2 + 1) ^ sx7) << 4));\
        half8 a0, a1;                                                        \
        a0[0]=(_Float16)f00[0]; a0[1]=(_Float16)f00[1];                      \
        a0[2]=(_Float16)f00[2]; a0[3]=(_Float16)f00[3];                      \
        a0[4]=(_Float16)f01[0]; a0[5]=(_Float16)f01[1];                      \
        a0[6]=(_Float16)f01[2]; a0[7]=(_Float16)f01[3];                      \
        a1[0]=(_Float16)f10[0]; a1[1]=(_Float16)f10[1];                      \
        a1[2]=(_Float16)f10[2]; a1[3]=(_Float16)f10[3];                      \
        a1[4]=(_Float16)f11[0]; a1[5]=(_Float16)f11[1];                      \
        a1[6]=(_Float16)f11[2]; a1[7]=(_Float16)f11[3];                      \
        __builtin_amdgcn_sched_barrier(0);                                   \
        DMAI;                                                                \
        __builtin_amdgcn_sched_barrier(0);                                   \
        _Pragma("unroll")                                                    \
        for (int ks = 0; ks < 2; ++ks) {                                     \
            _Pragma("unroll")                                                \
            for (int nb = 0; nb < 2; ++nb) {                                 \
                uint2v d = *(const uint2v*)(bl + (nb * 32 + ln) * 256        \
                             + ((((i_) * 2 + ks) ^ sx15) << 4) + hi * 8);    \
                unsigned q0 = ((d[0] & 0x000000FFu) << 8)  | ((d[0] & 0x0000FF00u) << 16); \
                unsigned q1 = ((d[0] & 0x00FF0000u) >> 8)  |  (d[0] & 0xFF000000u);        \
                unsigned q2 = ((d[1] & 0x000000FFu) << 8)  | ((d[1] & 0x0000FF00u) << 16); \
                unsigned q3 = ((d[1] & 0x00FF0000u) >> 8)  |  (d[1] & 0xFF000000u);        \
                uint4v qq = {q0, q1, q2, q3};                                \
                half8 b = __builtin_bit_cast(half8, qq);                     \
                acc[nb] = __builtin_amdgcn_mfma_f32_32x32x16_f16(            \
                              ks ? a1 : a0, b, acc[nb], 0, 0, 0);            \
            }                                                                \
        }                                                                    \
    } while (0)

    // 8 chunks; chunk c in buf c&1; DMA(c+2) only after chunk c's cvt consumed
    // the buffer it overwrites. vmcnt(4) keeps the next chunk's DMA in flight.
    /* chunks 0,1 drained by prologue */ CHUNK(0, 0, ADMA(2, 0));
    WAITV(4);  CHUNK(1, 1, ADMA(3, 1));
    WAITV(4);  CHUNK(2, 0, ADMA(4, 0));
    WAITV(4);  CHUNK(3, 1, ADMA(5, 1));
    WAITV(4);  CHUNK(4, 0, ADMA(6, 0));
    WAITV(4);  CHUNK(5, 1, ADMA(7, 1));
    WAITV(4);  CHUNK(6, 0, (void)0);
    WAITV(0);  CHUNK(7, 1, (void)0);

#undef ADMA
#undef WAITV
#undef CHUNK

    // ---- stores dead-last: nothing ever waits on them.
    // C layout: col = l&31, row = (r&3) + 8*(r>>2) + 4*(l>>5). ----
    float* op = out + (row0 + 4 * hi) * (long)N_DIM + nh * 64 + ln;
#pragma unroll
    for (int nb = 0; nb < 2; ++nb) {
#pragma unroll
        for (int r = 0; r < 16; ++r) {
            const int row = (r & 3) + 8 * (r >> 2);
            op[(long)row * N_DIM + nb * 32] = acc[nb][r];
        }
    }
}

extern "C" void kernel_launch(void* const* d_in, const int* in_sizes, int n_in,
                              void* d_out, int out_size, void* d_ws, size_t ws_size,
                              hipStream_t stream) {
    const float* x     = (const float*)d_in[0];
    const float* shift = (const float*)d_in[1];
    const float* sgn   = (const float*)d_in[2];
    const float* bias  = (const float*)d_in[3];
    float* out = (float*)d_out;
    unsigned char* wT8 = (unsigned char*)d_ws;   // 256*256 = 64 KB scratch

    build_wT8<<<256, 256, 0, stream>>>(shift, sgn, wT8);

    dense_shift_gemm<<<NBLK, 256, 0, stream>>>(x, wT8, bias, out);
}

// Round 13
// 198.906 us; speedup vs baseline: 1.2131x; 1.2131x over previous
//
#include <hip/hip_runtime.h>

typedef _Float16     half8    __attribute__((ext_vector_type(8)));
typedef float        floatx16 __attribute__((ext_vector_type(16)));
typedef float        float4v  __attribute__((ext_vector_type(4)));
typedef unsigned int uint2v   __attribute__((ext_vector_type(2)));
typedef unsigned int uint4v   __attribute__((ext_vector_type(4)));

#define K_DIM 256
#define N_DIM 256
#define NBLK  8192

typedef const __attribute__((address_space(1))) void global_cv_t;
typedef __attribute__((address_space(3))) void lds_v_t;

// W^T in bf8 (e5m2), PLAIN layout wT8[n*256+k]. EXACT: W = +-2^e, e in [-10,-1]
// -> e5m2 normal (exp field 5..14, mantissa 0); bf8->f16 is byte<<8 (exact).
__global__ __launch_bounds__(256) void build_wT8(const float* __restrict__ shift,
                                                 const float* __restrict__ sgn,
                                                 unsigned char* __restrict__ wT8) {
    int idx = blockIdx.x * 256 + threadIdx.x;   // idx = n*256 + k
    int n = idx >> 8, k = idx & 255;
    float sh = shift[k * 256 + n];
    float sg = sgn[k * 256 + n];
    int e = 15 + (int)sh;                       // e5m2 exponent field, 5..14
    wT8[idx] = (unsigned char)(((sg != 0.0f) ? 0x80 : 0) | (e << 2));
}

// R11 (best: 207.8 us) + non-temporal stores:
//  - block = 4 waves x 32 rows x 128 cols; 64 KB LDS -> 2 blocks/CU co-resident.
//  - the two col-half blocks of a row group land on the SAME XCD (bid 16m+8h+k
//    -> XCD k for both h), 8 dispatch slots apart -> second x-read is L2-hot.
//  - out is never re-read on-device: nt stores skip L2 write-allocate, leaving
//    the full 4 MB XCD-L2 for the x window the paired block re-reads.
//  - vmcnt domain = A-DMA only; one barrier total; per-wave self-sync after it.
__global__ __launch_bounds__(256, 2) void dense_shift_gemm(
        const float* __restrict__ x,
        const unsigned char* __restrict__ wT8,
        const float* __restrict__ bias,
        float* __restrict__ out) {

    // [0, 32K):  B bf8, this block's 128 cols. Local col c (256 B = 16 slots):
    //            phys slot s holds logical s^(c&15) (swizzle on DMA source).
    // [32K,64K): per-wave A f32, 2 buffers of [32 rows][128 B]; phys slot s of
    //            row r holds logical s^(r&7). DMA dest stays linear.
    __shared__ __align__(16) unsigned char lds[65536];

    const int t  = threadIdx.x;
    const int w  = t >> 6;            // wave 0..3
    const int l  = t & 63;
    const int ln = l & 31;
    const int hi = l >> 5;

    // ---- XCD-paired decomposition: bid = m*16 + nh*8 + k ----
    const int  bid  = blockIdx.x;
    const int  nh   = (bid >> 3) & 1;                      // column half (0/1)
    const long rg   = (long)(bid & 7) | ((long)(bid >> 4) << 3);  // row group
    const long row0 = (rg * 4 + w) * 32;                   // wave's 32 rows

    // bias first: oldest in FIFO, drained by the prologue vmcnt(0)
    float bv[4];
#pragma unroll
    for (int nb = 0; nb < 4; ++nb) bv[nb] = bias[nh * 128 + nb * 32 + ln];

    // ---- B DMA: 8 instrs/wave, 4 local cols each; source slot pre-XOR'd ----
    {
        const int nL  = l >> 4;       // col within quad
        const int t16 = l & 15;       // dest slot
#pragma unroll
        for (int i = 0; i < 8; ++i) {
            const int nc = w * 32 + i * 4 + nL;            // local col 0..127
            const unsigned char* g = wT8 + (nh * 128 + nc) * 256
                                         + ((t16 ^ (nc & 15)) << 4);
            __builtin_amdgcn_global_load_lds(
                (global_cv_t*)g,
                (lds_v_t*)(lds + (w * 32 + i * 4) * 256), 16, 0, 0);
        }
    }

    // ---- A DMA geometry: instr q covers rows q*8 + (l>>3), slot l&7;
    //      source slot pre-XOR'd by row&7 ----
    const int arow  = l >> 3;                 // 0..7
    const int aslot = l & 7;
    const float* axg = x + (row0 + arow) * (long)K_DIM + (aslot ^ arow) * 4;
    char* aw = (char*)lds + 32768 + w * 8192;

#define ADMA(c_, buf_) do {                                                  \
        _Pragma("unroll")                                                    \
        for (int q = 0; q < 4; ++q) {                                        \
            __builtin_amdgcn_global_load_lds(                                \
                (global_cv_t*)(axg + q * 8 * K_DIM + (c_) * 32),             \
                (lds_v_t*)(aw + (buf_) * 4096 + q * 1024), 16, 0, 0);        \
        }                                                                    \
    } while (0)

    ADMA(0, 0);
    ADMA(1, 1);

    asm volatile("s_waitcnt vmcnt(0)" ::: "memory");   // all DMA landed
    __syncthreads();                                   // the ONLY barrier

    floatx16 acc[4];
#pragma unroll
    for (int nb = 0; nb < 4; ++nb)
#pragma unroll
        for (int r = 0; r < 16; ++r) acc[nb][r] = bv[nb];   // bias pre-folded

    const char* bl    = (const char*)lds;
    const int   sx7   = ln & 7;
    const int   sx15  = ln & 15;
    const char* arp   = aw + ln * 128;        // this lane's A row (+ buf*4096)

#define WAITV(n_) do {                                                       \
        asm volatile("s_waitcnt vmcnt(" #n_ ")" ::: "memory");               \
        __builtin_amdgcn_sched_barrier(0);                                   \
    } while (0)

    // One K=32 chunk: A from own LDS buffer, cvt to f16, overwrite-DMA for
    // chunk i_+2, then B (b64 + exact bf8->f16 unpack) and 8 MFMA.
#define CHUNK(i_, buf_, DMAI) do {                                           \
        const char* ab_ = arp + (buf_) * 4096;                               \
        float4v f00 = *(const float4v*)(ab_ + (((hi * 2    ) ^ sx7) << 4));  \
        float4v f01 = *(const float4v*)(ab_ + (((hi * 2 + 1) ^ sx7) << 4));  \
        float4v f10 = *(const float4v*)(ab_ + (((4 + hi * 2    ) ^ sx7) << 4));\
        float4v f11 = *(const float4v*)(ab_ + (((4 + hi * 2 + 1) ^ sx7) << 4));\
        half8 a0, a1;                                                        \
        a0[0]=(_Float16)f00[0]; a0[1]=(_Float16)f00[1];                      \
        a0[2]=(_Float16)f00[2]; a0[3]=(_Float16)f00[3];                      \
        a0[4]=(_Float16)f01[0]; a0[5]=(_Float16)f01[1];                      \
        a0[6]=(_Float16)f01[2]; a0[7]=(_Float16)f01[3];                      \
        a1[0]=(_Float16)f10[0]; a1[1]=(_Float16)f10[1];                      \
        a1[2]=(_Float16)f10[2]; a1[3]=(_Float16)f10[3];                      \
        a1[4]=(_Float16)f11[0]; a1[5]=(_Float16)f11[1];                      \
        a1[6]=(_Float16)f11[2]; a1[7]=(_Float16)f11[3];                      \
        __builtin_amdgcn_sched_barrier(0);                                   \
        DMAI;                                                                \
        __builtin_amdgcn_sched_barrier(0);                                   \
        _Pragma("unroll")                                                    \
        for (int ks = 0; ks < 2; ++ks) {                                     \
            _Pragma("unroll")                                                \
            for (int nb = 0; nb < 4; ++nb) {                                 \
                uint2v d = *(const uint2v*)(bl + (nb * 32 + ln) * 256        \
                             + ((((i_) * 2 + ks) ^ sx15) << 4) + hi * 8);    \
                unsigned q0 = ((d[0] & 0x000000FFu) << 8)  | ((d[0] & 0x0000FF00u) << 16); \
                unsigned q1 = ((d[0] & 0x00FF0000u) >> 8)  |  (d[0] & 0xFF000000u);        \
                unsigned q2 = ((d[1] & 0x000000FFu) << 8)  | ((d[1] & 0x0000FF00u) << 16); \
                unsigned q3 = ((d[1] & 0x00FF0000u) >> 8)  |  (d[1] & 0xFF000000u);        \
                uint4v qq = {q0, q1, q2, q3};                                \
                half8 b = __builtin_bit_cast(half8, qq);                     \
                acc[nb] = __builtin_amdgcn_mfma_f32_32x32x16_f16(            \
                              ks ? a1 : a0, b, acc[nb], 0, 0, 0);            \
            }                                                                \
        }                                                                    \
    } while (0)

    // 8 chunks; chunk c in buf c&1; DMA(c+2) only after chunk c's cvt consumed
    // the buffer it overwrites. vmcnt(4) keeps the next chunk's DMA in flight.
    /* chunks 0,1 drained by prologue */ CHUNK(0, 0, ADMA(2, 0));
    WAITV(4);  CHUNK(1, 1, ADMA(3, 1));
    WAITV(4);  CHUNK(2, 0, ADMA(4, 0));
    WAITV(4);  CHUNK(3, 1, ADMA(5, 1));
    WAITV(4);  CHUNK(4, 0, ADMA(6, 0));
    WAITV(4);  CHUNK(5, 1, ADMA(7, 1));
    WAITV(4);  CHUNK(6, 0, (void)0);
    WAITV(0);  CHUNK(7, 1, (void)0);

#undef ADMA
#undef WAITV
#undef CHUNK

    // ---- stores dead-last, NON-TEMPORAL (out never re-read on device; skip
    // L2 write-allocate so the paired block's x window stays cached).
    // C layout: col = l&31, row = (r&3) + 8*(r>>2) + 4*(l>>5). ----
    float* op = out + (row0 + 4 * hi) * (long)N_DIM + nh * 128 + ln;
#pragma unroll
    for (int nb = 0; nb < 4; ++nb) {
#pragma unroll
        for (int r = 0; r < 16; ++r) {
            const int row = (r & 3) + 8 * (r >> 2);
            __builtin_nontemporal_store(acc[nb][r],
                                        &op[(long)row * N_DIM + nb * 32]);
        }
    }
}

extern "C" void kernel_launch(void* const* d_in, const int* in_sizes, int n_in,
                              void* d_out, int out_size, void* d_ws, size_t ws_size,
                              hipStream_t stream) {
    const float* x     = (const float*)d_in[0];
    const float* shift = (const float*)d_in[1];
    const float* sgn   = (const float*)d_in[2];
    const float* bias  = (const float*)d_in[3];
    float* out = (float*)d_out;
    unsigned char* wT8 = (unsigned char*)d_ws;   // 256*256 = 64 KB scratch

    build_wT8<<<256, 256, 0, stream>>>(shift, sgn, wT8);

    dense_shift_gemm<<<NBLK, 256, 0, stream>>>(x, wT8, bias, out);
}

// Round 14
// 195.627 us; speedup vs baseline: 1.2334x; 1.0168x over previous
//
#include <hip/hip_runtime.h>

typedef _Float16     half8    __attribute__((ext_vector_type(8)));
typedef float        floatx16 __attribute__((ext_vector_type(16)));
typedef float        float4v  __attribute__((ext_vector_type(4)));
typedef unsigned int uint2v   __attribute__((ext_vector_type(2)));
typedef unsigned int uint4v   __attribute__((ext_vector_type(4)));

#define K_DIM 256
#define N_DIM 256
#define NBLK  8192

typedef const __attribute__((address_space(1))) void global_cv_t;
typedef __attribute__((address_space(3))) void lds_v_t;

// W^T in bf8 (e5m2), PLAIN layout wT8[n*256+k]. EXACT: W = +-2^e, e in [-10,-1]
// -> e5m2 normal (exp field 5..14, mantissa 0); bf8->f16 is byte<<8 (exact).
__global__ __launch_bounds__(256) void build_wT8(const float* __restrict__ shift,
                                                 const float* __restrict__ sgn,
                                                 unsigned char* __restrict__ wT8) {
    int idx = blockIdx.x * 256 + threadIdx.x;   // idx = n*256 + k
    int n = idx >> 8, k = idx & 255;
    float sh = shift[k * 256 + n];
    float sg = sgn[k * 256 + n];
    int e = 15 + (int)sh;                       // e5m2 exponent field, 5..14
    wT8[idx] = (unsigned char)(((sg != 0.0f) ? 0x80 : 0) | (e << 2));
}

// R13 (best: 198.9 us) + 3-buffer A rotation (DMA lead = 2 chunks):
//  - block = 4 waves x 32 rows x 128 cols; 80 KB LDS -> 2 blocks/CU = 160 KB.
//  - col-half pairs land on the SAME XCD (bid = m*16 + nh*8 + k), so the
//    second x-read hits that XCD's L2; nt stores keep out of L2.
//  - vmcnt domain = A-DMA only; one barrier total; per-wave self-sync after it.
__global__ __launch_bounds__(256, 2) void dense_shift_gemm(
        const float* __restrict__ x,
        const unsigned char* __restrict__ wT8,
        const float* __restrict__ bias,
        float* __restrict__ out) {

    // [0, 32K):  B bf8, this block's 128 cols. Local col c (256 B = 16 slots):
    //            phys slot s holds logical s^(c&15) (swizzle on DMA source).
    // [32K,80K): per-wave A f32, 3 buffers of [32 rows][128 B]; phys slot s of
    //            row r holds logical s^(r&7). DMA dest stays linear.
    __shared__ __align__(16) unsigned char lds[81920];

    const int t  = threadIdx.x;
    const int w  = t >> 6;            // wave 0..3
    const int l  = t & 63;
    const int ln = l & 31;
    const int hi = l >> 5;

    // ---- XCD-paired decomposition: bid = m*16 + nh*8 + k ----
    const int  bid  = blockIdx.x;
    const int  nh   = (bid >> 3) & 1;                      // column half (0/1)
    const long rg   = (long)(bid & 7) | ((long)(bid >> 4) << 3);  // row group
    const long row0 = (rg * 4 + w) * 32;                   // wave's 32 rows

    // bias first: oldest in FIFO, drained by the prologue vmcnt(0)
    float bv[4];
#pragma unroll
    for (int nb = 0; nb < 4; ++nb) bv[nb] = bias[nh * 128 + nb * 32 + ln];

    // ---- B DMA: 8 instrs/wave, 4 local cols each; source slot pre-XOR'd ----
    {
        const int nL  = l >> 4;       // col within quad
        const int t16 = l & 15;       // dest slot
#pragma unroll
        for (int i = 0; i < 8; ++i) {
            const int nc = w * 32 + i * 4 + nL;            // local col 0..127
            const unsigned char* g = wT8 + (nh * 128 + nc) * 256
                                         + ((t16 ^ (nc & 15)) << 4);
            __builtin_amdgcn_global_load_lds(
                (global_cv_t*)g,
                (lds_v_t*)(lds + (w * 32 + i * 4) * 256), 16, 0, 0);
        }
    }

    // ---- A DMA geometry: instr q covers rows q*8 + (l>>3), slot l&7;
    //      source slot pre-XOR'd by row&7 ----
    const int arow  = l >> 3;                 // 0..7
    const int aslot = l & 7;
    const float* axg = x + (row0 + arow) * (long)K_DIM + (aslot ^ arow) * 4;
    char* aw = (char*)lds + 32768 + w * 12288;   // 3 x 4 KB per wave

#define ADMA(c_, buf_) do {                                                  \
        _Pragma("unroll")                                                    \
        for (int q = 0; q < 4; ++q) {                                        \
            __builtin_amdgcn_global_load_lds(                                \
                (global_cv_t*)(axg + q * 8 * K_DIM + (c_) * 32),             \
                (lds_v_t*)(aw + (buf_) * 4096 + q * 1024), 16, 0, 0);        \
        }                                                                    \
    } while (0)

    ADMA(0, 0);
    ADMA(1, 1);
    ADMA(2, 2);

    asm volatile("s_waitcnt vmcnt(0)" ::: "memory");   // all DMA landed
    __syncthreads();                                   // the ONLY barrier

    floatx16 acc[4];
#pragma unroll
    for (int nb = 0; nb < 4; ++nb)
#pragma unroll
        for (int r = 0; r < 16; ++r) acc[nb][r] = bv[nb];   // bias pre-folded

    const char* bl    = (const char*)lds;
    const int   sx7   = ln & 7;
    const int   sx15  = ln & 15;
    const char* arp   = aw + ln * 128;        // this lane's A row (+ buf*4096)

#define WAITV(n_) do {                                                       \
        asm volatile("s_waitcnt vmcnt(" #n_ ")" ::: "memory");               \
        __builtin_amdgcn_sched_barrier(0);                                   \
    } while (0)

    // One K=32 chunk: A from own LDS buffer, cvt to f16, overwrite-DMA for
    // chunk i_+3 (2-chunk lead), then B (b64 + exact bf8->f16) and 8 MFMA.
#define CHUNK(i_, buf_, DMAI) do {                                           \
        const char* ab_ = arp + (buf_) * 4096;                               \
        float4v f00 = *(const float4v*)(ab_ + (((hi * 2    ) ^ sx7) << 4));  \
        float4v f01 = *(const float4v*)(ab_ + (((hi * 2 + 1) ^ sx7) << 4));  \
        float4v f10 = *(const float4v*)(ab_ + (((4 + hi * 2    ) ^ sx7) << 4));\
        float4v f11 = *(const float4v*)(ab_ + (((4 + hi * 2 + 1) ^ sx7) << 4));\
        half8 a0, a1;                                                        \
        a0[0]=(_Float16)f00[0]; a0[1]=(_Float16)f00[1];                      \
        a0[2]=(_Float16)f00[2]; a0[3]=(_Float16)f00[3];                      \
        a0[4]=(_Float16)f01[0]; a0[5]=(_Float16)f01[1];                      \
        a0[6]=(_Float16)f01[2]; a0[7]=(_Float16)f01[3];                      \
        a1[0]=(_Float16)f10[0]; a1[1]=(_Float16)f10[1];                      \
        a1[2]=(_Float16)f10[2]; a1[3]=(_Float16)f10[3];                      \
        a1[4]=(_Float16)f11[0]; a1[5]=(_Float16)f11[1];                      \
        a1[6]=(_Float16)f11[2]; a1[7]=(_Float16)f11[3];                      \
        __builtin_amdgcn_sched_barrier(0);                                   \
        DMAI;                                                                \
        __builtin_amdgcn_sched_barrier(0);                                   \
        _Pragma("unroll")                                                    \
        for (int ks = 0; ks < 2; ++ks) {                                     \
            _Pragma("unroll")                                                \
            for (int nb = 0; nb < 4; ++nb) {                                 \
                uint2v d = *(const uint2v*)(bl + (nb * 32 + ln) * 256        \
                             + ((((i_) * 2 + ks) ^ sx15) << 4) + hi * 8);    \
                unsigned q0 = ((d[0] & 0x000000FFu) << 8)  | ((d[0] & 0x0000FF00u) << 16); \
                unsigned q1 = ((d[0] & 0x00FF0000u) >> 8)  |  (d[0] & 0xFF000000u);        \
                unsigned q2 = ((d[1] & 0x000000FFu) << 8)  | ((d[1] & 0x0000FF00u) << 16); \
                unsigned q3 = ((d[1] & 0x00FF0000u) >> 8)  |  (d[1] & 0xFF000000u);        \
                uint4v qq = {q0, q1, q2, q3};                                \
                half8 b = __builtin_bit_cast(half8, qq);                     \
                acc[nb] = __builtin_amdgcn_mfma_f32_32x32x16_f16(            \
                              ks ? a1 : a0, b, acc[nb], 0, 0, 0);            \
            }                                                                \
        }                                                                    \
    } while (0)

    // 8 chunks over 3 rotating buffers; ADMA(c+3) issued right after chunk c's
    // cvt consumed the buffer it overwrites -> every DMA has ~2 chunk-times
    // before its WAITV(8) (= 2 chunks / 8 ops may stay outstanding).
    CHUNK(0, 0, ADMA(3, 0));
    CHUNK(1, 1, ADMA(4, 1));
    CHUNK(2, 2, ADMA(5, 2));
    WAITV(8);  CHUNK(3, 0, ADMA(6, 0));
    WAITV(8);  CHUNK(4, 1, ADMA(7, 1));
    WAITV(8);  CHUNK(5, 2, (void)0);
    WAITV(4);  CHUNK(6, 0, (void)0);
    WAITV(0);  CHUNK(7, 1, (void)0);

#undef ADMA
#undef WAITV
#undef CHUNK

    // ---- stores dead-last, NON-TEMPORAL (out never re-read on device).
    // C layout: col = l&31, row = (r&3) + 8*(r>>2) + 4*(l>>5). ----
    float* op = out + (row0 + 4 * hi) * (long)N_DIM + nh * 128 + ln;
#pragma unroll
    for (int nb = 0; nb < 4; ++nb) {
#pragma unroll
        for (int r = 0; r < 16; ++r) {
            const int row = (r & 3) + 8 * (r >> 2);
            __builtin_nontemporal_store(acc[nb][r],
                                        &op[(long)row * N_DIM + nb * 32]);
        }
    }
}

extern "C" void kernel_launch(void* const* d_in, const int* in_sizes, int n_in,
                              void* d_out, int out_size, void* d_ws, size_t ws_size,
                              hipStream_t stream) {
    const float* x     = (const float*)d_in[0];
    const float* shift = (const float*)d_in[1];
    const float* sgn   = (const float*)d_in[2];
    const float* bias  = (const float*)d_in[3];
    float* out = (float*)d_out;
    unsigned char* wT8 = (unsigned char*)d_ws;   // 256*256 = 64 KB scratch

    build_wT8<<<256, 256, 0, stream>>>(shift, sgn, wT8);

    dense_shift_gemm<<<NBLK, 256, 0, stream>>>(x, wT8, bias, out);
}